// Round 1
// baseline (938.883 us; speedup 1.0000x reference)
//
#include <hip/hip_runtime.h>

// Problem constants (from reference): SIZE=65536 nodes, MAX_EDGES=16777216.
// Inputs (d_in order): x[65536] f32, edge_weights[16777216] f32,
//                      bias[65536] f32, src[16777216] i32, dst[16777216] i32.
// Output: out[65536] f32 = segment_sum(x[src]*w, dst) + bias.

#define NNODES 65536
#define NEDGES 16777216

// out is re-poisoned to 0xAA before every timed launch -> must init to bias.
__global__ __launch_bounds__(256) void init_out_kernel(
    const float* __restrict__ bias, float* __restrict__ out)
{
    int i = blockIdx.x * blockDim.x + threadIdx.x;
    if (i < NNODES) out[i] = bias[i];
}

// One thread handles 4 edges per grid-stride iteration via int4/float4 loads.
// x gather hits L2 (256 KB table); scatter is device-scope fire-and-forget
// global_atomic_add_f32 (return value unused -> no-return encoding).
__global__ __launch_bounds__(256) void edge_kernel(
    const float* __restrict__ x,
    const float* __restrict__ w,
    const int*   __restrict__ src,
    const int*   __restrict__ dst,
    float*       __restrict__ out)
{
    const int n4 = NEDGES / 4;
    int tid    = blockIdx.x * blockDim.x + threadIdx.x;
    int stride = gridDim.x * blockDim.x;

    for (int i = tid; i < n4; i += stride) {
        int4   s  = ((const int4*)src)[i];
        int4   d  = ((const int4*)dst)[i];
        float4 ww = ((const float4*)w)[i];

        float vx = x[s.x] * ww.x;
        float vy = x[s.y] * ww.y;
        float vz = x[s.z] * ww.z;
        float vw = x[s.w] * ww.w;

        atomicAdd(&out[d.x], vx);
        atomicAdd(&out[d.y], vy);
        atomicAdd(&out[d.z], vz);
        atomicAdd(&out[d.w], vw);
    }
}

extern "C" void kernel_launch(void* const* d_in, const int* in_sizes, int n_in,
                              void* d_out, int out_size, void* d_ws, size_t ws_size,
                              hipStream_t stream) {
    const float* x    = (const float*)d_in[0];
    const float* w    = (const float*)d_in[1];
    const float* bias = (const float*)d_in[2];
    const int*   src  = (const int*)d_in[3];
    const int*   dst  = (const int*)d_in[4];
    float* out = (float*)d_out;

    // 1) out = bias
    init_out_kernel<<<NNODES / 256, 256, 0, stream>>>(bias, out);

    // 2) scatter-add over edges. 4 edges/thread/iter; 4096 blocks x 256 thr
    //    = 1M threads -> 4 iterations each. Plenty of waves to hide the
    //    gather/atomic latency (256 CUs x 32 waves = 512K resident threads).
    edge_kernel<<<4096, 256, 0, stream>>>(x, w, src, dst, out);
}

// Round 2
// 349.107 us; speedup vs baseline: 2.6894x; 2.6894x over previous
//
#include <hip/hip_runtime.h>

// SIZE=65536 nodes, MAX_EDGES=16777216.
// Inputs: x[65536] f32, edge_weights[16M] f32, bias[65536] f32,
//         src[16M] i32, dst[16M] i32.
// Output: out[65536] f32 = segment_sum(x[src]*w, dst) + bias.
//
// Round-1 lesson: global fp32 atomics run at ~20.6 G/s and emit a ~32B HBM
// write each (WRITE_SIZE 510 MB). Strategy: LDS-privatized histograms,
// R=4 output ranges x 64KB LDS, private ws copies, non-atomic flush, then
// a tree-reduce kernel. Zero global atomics in the fast path.

#define NNODES 65536
#define NEDGES 16777216
#define RANGES 4
#define BINS   (NNODES / RANGES)   // 16384 bins -> 64 KB static LDS
#define THREADS 1024

// Stage 1: block b -> chunk c = b/RANGES... we use r = b & 3, c = b >> 2.
// Block (c,r) scans chunk c of the edge list (grid-strided by B chunks),
// keeps LDS histogram of dst range [r*BINS, (r+1)*BINS), then writes the
// bins to private copy ws[c*NNODES + r*BINS ...] (no atomics).
__global__ __launch_bounds__(THREADS) void hist_kernel(
    const float* __restrict__ x,
    const float* __restrict__ w,
    const int*   __restrict__ src,
    const int*   __restrict__ dst,
    float*       __restrict__ ws,
    int B)
{
    __shared__ float h[BINS];

    const int b  = blockIdx.x;
    const int r  = b & (RANGES - 1);
    const int c  = b >> 2;             // log2(RANGES)
    const int lo = r * BINS;

    for (int i = threadIdx.x; i < BINS; i += THREADS) h[i] = 0.0f;
    __syncthreads();

    const int n4 = NEDGES / 4;
    for (int g = c * THREADS + (int)threadIdx.x; g < n4; g += B * THREADS) {
        int4   s4 = ((const int4*)src)[g];
        int4   d4 = ((const int4*)dst)[g];
        float4 w4 = ((const float4*)w)[g];

        unsigned b0 = (unsigned)(d4.x - lo);
        unsigned b1 = (unsigned)(d4.y - lo);
        unsigned b2 = (unsigned)(d4.z - lo);
        unsigned b3 = (unsigned)(d4.w - lo);
        if (b0 < (unsigned)BINS) atomicAdd(&h[b0], x[s4.x] * w4.x);
        if (b1 < (unsigned)BINS) atomicAdd(&h[b1], x[s4.y] * w4.y);
        if (b2 < (unsigned)BINS) atomicAdd(&h[b2], x[s4.z] * w4.z);
        if (b3 < (unsigned)BINS) atomicAdd(&h[b3], x[s4.w] * w4.w);
    }
    __syncthreads();

    float* outc = ws + (size_t)c * NNODES + lo;
    for (int i = threadIdx.x; i < BINS; i += THREADS) outc[i] = h[i];
}

// Stage 2: out[i] = bias[i] + sum_c ws[c][i]. Coalesced: consecutive threads
// read consecutive i within each copy.
__global__ __launch_bounds__(256) void reduce_kernel(
    const float* __restrict__ ws,
    const float* __restrict__ bias,
    float*       __restrict__ out,
    int B)
{
    int i = blockIdx.x * 256 + threadIdx.x;
    float acc = bias[i];
    for (int c = 0; c < B; ++c) acc += ws[(size_t)c * NNODES + i];
    out[i] = acc;
}

// Fallback (ws too small): round-1 global-atomic version. Correct, slow.
__global__ __launch_bounds__(256) void init_out_kernel(
    const float* __restrict__ bias, float* __restrict__ out)
{
    int i = blockIdx.x * blockDim.x + threadIdx.x;
    if (i < NNODES) out[i] = bias[i];
}

__global__ __launch_bounds__(256) void edge_atomic_kernel(
    const float* __restrict__ x, const float* __restrict__ w,
    const int* __restrict__ src, const int* __restrict__ dst,
    float* __restrict__ out)
{
    const int n4 = NEDGES / 4;
    int tid = blockIdx.x * blockDim.x + threadIdx.x;
    int stride = gridDim.x * blockDim.x;
    for (int i = tid; i < n4; i += stride) {
        int4 s = ((const int4*)src)[i];
        int4 d = ((const int4*)dst)[i];
        float4 ww = ((const float4*)w)[i];
        atomicAdd(&out[d.x], x[s.x] * ww.x);
        atomicAdd(&out[d.y], x[s.y] * ww.y);
        atomicAdd(&out[d.z], x[s.z] * ww.z);
        atomicAdd(&out[d.w], x[s.w] * ww.w);
    }
}

extern "C" void kernel_launch(void* const* d_in, const int* in_sizes, int n_in,
                              void* d_out, int out_size, void* d_ws, size_t ws_size,
                              hipStream_t stream) {
    const float* x    = (const float*)d_in[0];
    const float* w    = (const float*)d_in[1];
    const float* bias = (const float*)d_in[2];
    const int*   src  = (const int*)d_in[3];
    const int*   dst  = (const int*)d_in[4];
    float* out = (float*)d_out;
    float* ws  = (float*)d_ws;

    // B private full-output copies of 256 KB each; want B=128 (32 MB ws).
    size_t copies = ws_size / ((size_t)NNODES * sizeof(float));
    int B = (int)(copies < 128 ? copies : 128);

    if (B >= 1) {
        // 2 blocks/CU at B=128 (512 blocks, 64 KB LDS each).
        hist_kernel<<<B * RANGES, THREADS, 0, stream>>>(x, w, src, dst, ws, B);
        reduce_kernel<<<NNODES / 256, 256, 0, stream>>>(ws, bias, out, B);
    } else {
        init_out_kernel<<<NNODES / 256, 256, 0, stream>>>(bias, out);
        edge_atomic_kernel<<<4096, 256, 0, stream>>>(x, w, src, dst, out);
    }
}

// Round 3
// 313.768 us; speedup vs baseline: 2.9923x; 1.1126x over previous
//
#include <hip/hip_runtime.h>

// SIZE=65536 nodes, MAX_EDGES=16777216.
// out[i] = bias[i] + sum over edges e with dst[e]==i of x[src[e]]*w[e].
//
// R1 lesson: global fp32 atomics ~20.6 G/s, ~32B HBM write each. -> LDS hist.
// R2 lesson: (a) reduce_kernel was latency-bound (128-deep dep chain, 1
// block/CU) -> 2-stage tree. (b) hist inner loop serialized 4 guarded
// gather->wait->ds_atomic round trips -> batch guarded gathers, then
// batch guarded atomics (one vmcnt wait per 8 edges).

#define NNODES  65536
#define NEDGES  16777216
#define RANGES  4
#define BINS    (NNODES / RANGES)   // 16384 bins -> 64 KB LDS, 2 blocks/CU
#define THREADS 1024
#define NCOPIES 128                 // private output copies in ws (32 MB)
#define GROUPS  16
#define CPG     (NCOPIES / GROUPS)  // 8 copies per reduce group

// ---------------- Stage 1: LDS histograms ----------------
// Block b: range r = b&3, chunk c = b>>2. Scans chunk c of the edge list,
// accumulates dst in [r*BINS,(r+1)*BINS) into LDS, flushes (non-atomic) to
// private copy ws[c]. 8 edges per thread-iteration for ILP.
__global__ __launch_bounds__(THREADS, 8) void hist_kernel(
    const float* __restrict__ x,
    const float* __restrict__ w,
    const int*   __restrict__ src,
    const int*   __restrict__ dst,
    float*       __restrict__ ws,
    int B)
{
    __shared__ float h[BINS];

    const int b  = blockIdx.x;
    const int r  = b & (RANGES - 1);
    const int c  = b >> 2;
    const int lo = r * BINS;

    for (int i = threadIdx.x; i < BINS; i += THREADS) h[i] = 0.0f;
    __syncthreads();

    const int4*   src4 = (const int4*)src;
    const int4*   dst4 = (const int4*)dst;
    const float4* wgt4 = (const float4*)w;

    const int n8 = NEDGES / 8;
    for (int g = c * THREADS + (int)threadIdx.x; g < n8; g += B * THREADS) {
        int4   sa = src4[2 * g], sb = src4[2 * g + 1];
        int4   da = dst4[2 * g], db = dst4[2 * g + 1];
        float4 wa = wgt4[2 * g], wb = wgt4[2 * g + 1];

        int      s[8]  = { sa.x, sa.y, sa.z, sa.w, sb.x, sb.y, sb.z, sb.w };
        unsigned bin[8] = {
            (unsigned)(da.x - lo), (unsigned)(da.y - lo),
            (unsigned)(da.z - lo), (unsigned)(da.w - lo),
            (unsigned)(db.x - lo), (unsigned)(db.y - lo),
            (unsigned)(db.z - lo), (unsigned)(db.w - lo) };
        float    wv[8] = { wa.x, wa.y, wa.z, wa.w, wb.x, wb.y, wb.z, wb.w };

        // Pass 1: guarded gathers only (loads group under one vmcnt wait).
        float v[8];
        #pragma unroll
        for (int k = 0; k < 8; ++k) {
            v[k] = 0.0f;
            if (bin[k] < (unsigned)BINS) v[k] = x[s[k]] * wv[k];
        }
        // Pass 2: guarded LDS atomics (fire-and-forget).
        #pragma unroll
        for (int k = 0; k < 8; ++k) {
            if (bin[k] < (unsigned)BINS) atomicAdd(&h[bin[k]], v[k]);
        }
    }
    __syncthreads();

    float* outc = ws + (size_t)c * NNODES + lo;
    for (int i = threadIdx.x; i < BINS; i += THREADS) outc[i] = h[i];
}

// ---------------- Stage 2a: tree reduce 128 -> 16 (in-place) ----------------
// Block = (group g, slice jb). Sums copies [g*CPG, (g+1)*CPG) for 1024 floats
// (256 threads x float4), writes result into copy g*CPG. No cross-block
// aliasing: each (g, i) owned by exactly one thread.
__global__ __launch_bounds__(256) void reduceA_kernel(float* __restrict__ ws)
{
    const int NB = NNODES / (256 * 4);          // 64 slice-blocks per group
    int g  = blockIdx.x / NB;
    int jb = blockIdx.x % NB;
    int i4 = jb * 256 + (int)threadIdx.x;       // float4 index in [0, 16384)

    float4* w4 = (float4*)ws;
    const int stride4 = NNODES / 4;

    float4 acc = w4[(size_t)(g * CPG) * stride4 + i4];
    #pragma unroll
    for (int cc = 1; cc < CPG; ++cc) {
        float4 t = w4[(size_t)(g * CPG + cc) * stride4 + i4];
        acc.x += t.x; acc.y += t.y; acc.z += t.z; acc.w += t.w;
    }
    w4[(size_t)(g * CPG) * stride4 + i4] = acc;
}

// ---------------- Stage 2b: 16 partials + bias -> out ----------------
__global__ __launch_bounds__(256) void reduceB_kernel(
    const float* __restrict__ ws,
    const float* __restrict__ bias,
    float*       __restrict__ out)
{
    int i4 = blockIdx.x * 256 + (int)threadIdx.x;  // float4 index
    const float4* w4 = (const float4*)ws;
    const int stride4 = NNODES / 4;

    float4 acc = ((const float4*)bias)[i4];
    #pragma unroll
    for (int g = 0; g < GROUPS; ++g) {
        float4 t = w4[(size_t)(g * CPG) * stride4 + i4];
        acc.x += t.x; acc.y += t.y; acc.z += t.z; acc.w += t.w;
    }
    ((float4*)out)[i4] = acc;
}

// ---------------- Generic fallback reduce (B != NCOPIES) ----------------
__global__ __launch_bounds__(256) void reduce_generic_kernel(
    const float* __restrict__ ws,
    const float* __restrict__ bias,
    float*       __restrict__ out,
    int B)
{
    int i = blockIdx.x * 256 + (int)threadIdx.x;
    float acc = bias[i];
    for (int cc = 0; cc < B; ++cc) acc += ws[(size_t)cc * NNODES + i];
    out[i] = acc;
}

// ---------------- Fallback: global atomics (tiny ws) ----------------
__global__ __launch_bounds__(256) void init_out_kernel(
    const float* __restrict__ bias, float* __restrict__ out)
{
    int i = blockIdx.x * blockDim.x + threadIdx.x;
    if (i < NNODES) out[i] = bias[i];
}

__global__ __launch_bounds__(256) void edge_atomic_kernel(
    const float* __restrict__ x, const float* __restrict__ w,
    const int* __restrict__ src, const int* __restrict__ dst,
    float* __restrict__ out)
{
    const int n4 = NEDGES / 4;
    int tid = blockIdx.x * blockDim.x + threadIdx.x;
    int stride = gridDim.x * blockDim.x;
    for (int i = tid; i < n4; i += stride) {
        int4 s = ((const int4*)src)[i];
        int4 d = ((const int4*)dst)[i];
        float4 ww = ((const float4*)w)[i];
        atomicAdd(&out[d.x], x[s.x] * ww.x);
        atomicAdd(&out[d.y], x[s.y] * ww.y);
        atomicAdd(&out[d.z], x[s.z] * ww.z);
        atomicAdd(&out[d.w], x[s.w] * ww.w);
    }
}

extern "C" void kernel_launch(void* const* d_in, const int* in_sizes, int n_in,
                              void* d_out, int out_size, void* d_ws, size_t ws_size,
                              hipStream_t stream) {
    const float* x    = (const float*)d_in[0];
    const float* w    = (const float*)d_in[1];
    const float* bias = (const float*)d_in[2];
    const int*   src  = (const int*)d_in[3];
    const int*   dst  = (const int*)d_in[4];
    float* out = (float*)d_out;
    float* ws  = (float*)d_ws;

    size_t copies = ws_size / ((size_t)NNODES * sizeof(float));
    int B = (int)(copies < NCOPIES ? copies : NCOPIES);

    if (B >= 1) {
        hist_kernel<<<B * RANGES, THREADS, 0, stream>>>(x, w, src, dst, ws, B);
        if (B == NCOPIES) {
            reduceA_kernel<<<GROUPS * (NNODES / 1024), 256, 0, stream>>>(ws);
            reduceB_kernel<<<NNODES / 1024, 256, 0, stream>>>(ws, bias, out);
        } else {
            reduce_generic_kernel<<<NNODES / 256, 256, 0, stream>>>(ws, bias, out, B);
        }
    } else {
        init_out_kernel<<<NNODES / 256, 256, 0, stream>>>(bias, out);
        edge_atomic_kernel<<<4096, 256, 0, stream>>>(x, w, src, dst, out);
    }
}

// Round 4
// 272.672 us; speedup vs baseline: 3.4433x; 1.1507x over previous
//
#include <hip/hip_runtime.h>

// SIZE=65536 nodes, MAX_EDGES=16777216.
// out[i] = bias[i] + sum over edges e with dst[e]==i of x[src[e]]*w[e].
//
// R1: global fp32 atomics ~20.6 G/s, ~32B HBM write each -> LDS histograms.
// R2: batched guarded gathers / ds_adds (one vmcnt wait per 8 edges).
// R3: discovered ~135us constant harness overhead; hist is the only real
//     cost. RANGES 4->2 via 128KB dynamic LDS: halves redundant edge-stream
//     reads (768->384 MB logical) and doubles guard lane-efficiency.

#define NNODES  65536
#define NEDGES  16777216
#define RANGES  2
#define BINS    (NNODES / RANGES)   // 32768 bins -> 128 KB dynamic LDS
#define THREADS 1024
#define NCOPIES 128                 // private output copies in ws (32 MB)
#define GROUPS  16
#define CPG     (NCOPIES / GROUPS)  // 8 copies per reduce group

// ---------------- Stage 1: LDS histograms ----------------
// Block b: range r = b&1, chunk c = b>>1. Scans chunk c of the edge list,
// accumulates dst in [r*BINS,(r+1)*BINS) into a 128KB LDS histogram, then
// flushes (non-atomic) to private copy ws[c]. 8 edges per thread-iteration.
__global__ __launch_bounds__(THREADS, 4) void hist_kernel(
    const float* __restrict__ x,
    const float* __restrict__ w,
    const int*   __restrict__ src,
    const int*   __restrict__ dst,
    float*       __restrict__ ws,
    int B)
{
    extern __shared__ float h[];   // BINS floats = 128 KB

    const int b  = blockIdx.x;
    const int r  = b & (RANGES - 1);
    const int c  = b >> 1;
    const int lo = r * BINS;

    for (int i = threadIdx.x; i < BINS; i += THREADS) h[i] = 0.0f;
    __syncthreads();

    const int4*   src4 = (const int4*)src;
    const int4*   dst4 = (const int4*)dst;
    const float4* wgt4 = (const float4*)w;

    const int n8 = NEDGES / 8;
    for (int g = c * THREADS + (int)threadIdx.x; g < n8; g += B * THREADS) {
        int4   sa = src4[2 * g], sb = src4[2 * g + 1];
        int4   da = dst4[2 * g], db = dst4[2 * g + 1];
        float4 wa = wgt4[2 * g], wb = wgt4[2 * g + 1];

        int      s[8]  = { sa.x, sa.y, sa.z, sa.w, sb.x, sb.y, sb.z, sb.w };
        unsigned bin[8] = {
            (unsigned)(da.x - lo), (unsigned)(da.y - lo),
            (unsigned)(da.z - lo), (unsigned)(da.w - lo),
            (unsigned)(db.x - lo), (unsigned)(db.y - lo),
            (unsigned)(db.z - lo), (unsigned)(db.w - lo) };
        float    wv[8] = { wa.x, wa.y, wa.z, wa.w, wb.x, wb.y, wb.z, wb.w };

        // Pass 1: guarded gathers only (group under one vmcnt wait).
        float v[8];
        #pragma unroll
        for (int k = 0; k < 8; ++k) {
            v[k] = 0.0f;
            if (bin[k] < (unsigned)BINS) v[k] = x[s[k]] * wv[k];
        }
        // Pass 2: guarded LDS atomics (fire-and-forget).
        #pragma unroll
        for (int k = 0; k < 8; ++k) {
            if (bin[k] < (unsigned)BINS) atomicAdd(&h[bin[k]], v[k]);
        }
    }
    __syncthreads();

    float* outc = ws + (size_t)c * NNODES + lo;
    for (int i = threadIdx.x; i < BINS; i += THREADS) outc[i] = h[i];
}

// ---------------- Stage 2a: tree reduce 128 -> 16 (in-place) ----------------
__global__ __launch_bounds__(256) void reduceA_kernel(float* __restrict__ ws)
{
    const int NB = NNODES / (256 * 4);          // 64 slice-blocks per group
    int g  = blockIdx.x / NB;
    int jb = blockIdx.x % NB;
    int i4 = jb * 256 + (int)threadIdx.x;       // float4 index in [0, 16384)

    float4* w4 = (float4*)ws;
    const int stride4 = NNODES / 4;

    float4 acc = w4[(size_t)(g * CPG) * stride4 + i4];
    #pragma unroll
    for (int cc = 1; cc < CPG; ++cc) {
        float4 t = w4[(size_t)(g * CPG + cc) * stride4 + i4];
        acc.x += t.x; acc.y += t.y; acc.z += t.z; acc.w += t.w;
    }
    w4[(size_t)(g * CPG) * stride4 + i4] = acc;
}

// ---------------- Stage 2b: 16 partials + bias -> out ----------------
__global__ __launch_bounds__(256) void reduceB_kernel(
    const float* __restrict__ ws,
    const float* __restrict__ bias,
    float*       __restrict__ out)
{
    int i4 = blockIdx.x * 256 + (int)threadIdx.x;  // float4 index
    const float4* w4 = (const float4*)ws;
    const int stride4 = NNODES / 4;

    float4 acc = ((const float4*)bias)[i4];
    #pragma unroll
    for (int g = 0; g < GROUPS; ++g) {
        float4 t = w4[(size_t)(g * CPG) * stride4 + i4];
        acc.x += t.x; acc.y += t.y; acc.z += t.z; acc.w += t.w;
    }
    ((float4*)out)[i4] = acc;
}

// ---------------- Generic fallback reduce (B != NCOPIES) ----------------
__global__ __launch_bounds__(256) void reduce_generic_kernel(
    const float* __restrict__ ws,
    const float* __restrict__ bias,
    float*       __restrict__ out,
    int B)
{
    int i = blockIdx.x * 256 + (int)threadIdx.x;
    float acc = bias[i];
    for (int cc = 0; cc < B; ++cc) acc += ws[(size_t)cc * NNODES + i];
    out[i] = acc;
}

// ---------------- Fallback: global atomics (tiny ws) ----------------
__global__ __launch_bounds__(256) void init_out_kernel(
    const float* __restrict__ bias, float* __restrict__ out)
{
    int i = blockIdx.x * blockDim.x + threadIdx.x;
    if (i < NNODES) out[i] = bias[i];
}

__global__ __launch_bounds__(256) void edge_atomic_kernel(
    const float* __restrict__ x, const float* __restrict__ w,
    const int* __restrict__ src, const int* __restrict__ dst,
    float* __restrict__ out)
{
    const int n4 = NEDGES / 4;
    int tid = blockIdx.x * blockDim.x + threadIdx.x;
    int stride = gridDim.x * blockDim.x;
    for (int i = tid; i < n4; i += stride) {
        int4 s = ((const int4*)src)[i];
        int4 d = ((const int4*)dst)[i];
        float4 ww = ((const float4*)w)[i];
        atomicAdd(&out[d.x], x[s.x] * ww.x);
        atomicAdd(&out[d.y], x[s.y] * ww.y);
        atomicAdd(&out[d.z], x[s.z] * ww.z);
        atomicAdd(&out[d.w], x[s.w] * ww.w);
    }
}

extern "C" void kernel_launch(void* const* d_in, const int* in_sizes, int n_in,
                              void* d_out, int out_size, void* d_ws, size_t ws_size,
                              hipStream_t stream) {
    const float* x    = (const float*)d_in[0];
    const float* w    = (const float*)d_in[1];
    const float* bias = (const float*)d_in[2];
    const int*   src  = (const int*)d_in[3];
    const int*   dst  = (const int*)d_in[4];
    float* out = (float*)d_out;
    float* ws  = (float*)d_ws;

    size_t copies = ws_size / ((size_t)NNODES * sizeof(float));
    int B = (int)(copies < NCOPIES ? copies : NCOPIES);

    if (B >= 1) {
        // 256 blocks (B=128 x 2 ranges), 1 block/CU, 128 KB dynamic LDS.
        hist_kernel<<<B * RANGES, THREADS, BINS * sizeof(float), stream>>>(
            x, w, src, dst, ws, B);
        if (B == NCOPIES) {
            reduceA_kernel<<<GROUPS * (NNODES / 1024), 256, 0, stream>>>(ws);
            reduceB_kernel<<<NNODES / 1024, 256, 0, stream>>>(ws, bias, out);
        } else {
            reduce_generic_kernel<<<NNODES / 256, 256, 0, stream>>>(ws, bias, out, B);
        }
    } else {
        init_out_kernel<<<NNODES / 256, 256, 0, stream>>>(bias, out);
        edge_atomic_kernel<<<4096, 256, 0, stream>>>(x, w, src, dst, out);
    }
}